// Round 2
// baseline (975.474 us; speedup 1.0000x reference)
//
#include <hip/hip_runtime.h>

#define T_ 4
#define S_ 2048
#define D_ 768
#define SD_ (S_ * D_)          // 1572864
#define TSD_ (T_ * SD_)        // 6291456
#define H_ 12
#define HD_ 64

// ---------------------------------------------------------------------------
// 1) if_node over x -> tmp (binary spikes in fp32). fp64 membrane so the scan
//    is bit-identical to a float64 numpy reference.
// ---------------------------------------------------------------------------
__global__ __launch_bounds__(256) void k_ifnode_x(const float* __restrict__ x,
                                                  float* __restrict__ tmp) {
    int i = blockIdx.x * blockDim.x + threadIdx.x;
    int idx = i * 4;
    if (idx >= SD_) return;
    double v[4] = {0.0, 0.0, 0.0, 0.0};
#pragma unroll
    for (int t = 0; t < T_; t++) {
        float4 xt = *(const float4*)(x + (size_t)t * SD_ + idx);
        float xs[4] = {xt.x, xt.y, xt.z, xt.w};
        float4 sp;
        float* so = &sp.x;
#pragma unroll
        for (int j = 0; j < 4; j++) {
            v[j] += (double)xs[j];
            float s = (v[j] >= 1.0) ? 1.0f : 0.0f;
            so[j] = s;
            if (s > 0.f) v[j] = 0.0;
        }
        *(float4*)(tmp + (size_t)t * SD_ + idx) = sp;
    }
}

// ---------------------------------------------------------------------------
// 2) GEMM with fp64 accumulation: C = A(MxK) @ B(KxN), fp32 in/out.
//    64x64 tile, BK=16, 256 thr, 4x4 micro-tile. z selects (B,C) pair.
// ---------------------------------------------------------------------------
#define BM 64
#define BN 64
#define BK 16

__global__ __launch_bounds__(256) void k_gemm(
    const float* __restrict__ A,
    const float* __restrict__ B0, const float* __restrict__ B1,
    const float* __restrict__ B2,
    float* __restrict__ C0, float* __restrict__ C1, float* __restrict__ C2,
    int M, int N, int K) {
    const float* B = (blockIdx.z == 0) ? B0 : (blockIdx.z == 1) ? B1 : B2;
    float* C = (blockIdx.z == 0) ? C0 : (blockIdx.z == 1) ? C1 : C2;

    __shared__ float As[BK][BM + 4];
    __shared__ float Bs[BK][BN + 4];

    int tid = threadIdx.x;
    int tx = tid & 15;        // N-dir micro tile
    int ty = tid >> 4;        // M-dir micro tile
    int row0 = blockIdx.x * BM;
    int col0 = blockIdx.y * BN;

    int ar = tid >> 2;
    int ac = (tid & 3) * 4;
    int br = tid >> 4;
    int bc = (tid & 15) * 4;

    double acc[4][4] = {};

    for (int k0 = 0; k0 < K; k0 += BK) {
        float4 av = *(const float4*)(A + (size_t)(row0 + ar) * K + k0 + ac);
        As[ac + 0][ar] = av.x;
        As[ac + 1][ar] = av.y;
        As[ac + 2][ar] = av.z;
        As[ac + 3][ar] = av.w;
        float4 bv = *(const float4*)(B + (size_t)(k0 + br) * N + col0 + bc);
        *(float4*)&Bs[br][bc] = bv;
        __syncthreads();
#pragma unroll
        for (int kk = 0; kk < BK; kk++) {
            float4 a = *(const float4*)&As[kk][ty * 4];
            float4 b = *(const float4*)&Bs[kk][tx * 4];
            double aa[4] = {(double)a.x, (double)a.y, (double)a.z, (double)a.w};
            double bb[4] = {(double)b.x, (double)b.y, (double)b.z, (double)b.w};
#pragma unroll
            for (int i = 0; i < 4; i++)
#pragma unroll
                for (int j = 0; j < 4; j++) acc[i][j] = fma(aa[i], bb[j], acc[i][j]);
        }
        __syncthreads();
    }
#pragma unroll
    for (int i = 0; i < 4; i++) {
        int row = row0 + ty * 4 + i;
        float4 o = make_float4((float)acc[i][0], (float)acc[i][1],
                               (float)acc[i][2], (float)acc[i][3]);
        *(float4*)(C + (size_t)row * N + col0 + tx * 4) = o;
    }
}

// ---------------------------------------------------------------------------
// 3) Fused BatchNorm1d (per-s stats over T x D, fp64) + if_node (fp64). In place.
// ---------------------------------------------------------------------------
__global__ __launch_bounds__(256) void k_bn_if(float* __restrict__ Q,
                                               float* __restrict__ Kt,
                                               float* __restrict__ V) {
    int s = blockIdx.x;
    float* X = (blockIdx.y == 0) ? Q : (blockIdx.y == 1) ? Kt : V;

    __shared__ float buf[T_][D_];
    __shared__ double red[16];

    int tid = threadIdx.x;
    double sum = 0.0, sumsq = 0.0;
#pragma unroll
    for (int t = 0; t < T_; t++) {
        for (int d = tid; d < D_; d += 256) {
            float v = X[(size_t)t * SD_ + (size_t)s * D_ + d];
            buf[t][d] = v;
            double dv = (double)v;
            sum += dv;
            sumsq += dv * dv;
        }
    }
#pragma unroll
    for (int off = 32; off > 0; off >>= 1) {
        sum += __shfl_down(sum, off);
        sumsq += __shfl_down(sumsq, off);
    }
    int lane = tid & 63, wv = tid >> 6;
    if (lane == 0) { red[wv] = sum; red[4 + wv] = sumsq; }
    __syncthreads();
    if (tid == 0) {
        double s4 = red[0] + red[1] + red[2] + red[3];
        double q4 = red[4] + red[5] + red[6] + red[7];
        double mean = s4 / 3072.0;
        double var = q4 / 3072.0 - mean * mean;
        red[8] = mean;
        red[9] = 1.0 / sqrt(var + 1e-5);
    }
    __syncthreads();
    double mean = red[8], rstd = red[9];
    for (int d = tid; d < D_; d += 256) {
        double v = 0.0;
#pragma unroll
        for (int t = 0; t < T_; t++) {
            double xn = ((double)buf[t][d] - mean) * rstd;
            v += xn;
            float sp = (v >= 1.0) ? 1.0f : 0.0f;
            X[(size_t)t * SD_ + (size_t)s * D_ + d] = sp;
            if (sp > 0.f) v = 0.0;
        }
    }
}

// ---------------------------------------------------------------------------
// 4) QK[t,h,d] += sum_{s in chunk} Q*K. Binary products -> integer sums,
//    exact in fp32 at any order -> atomicAdd is deterministic here.
//    grid.x = T_*H_*16 chunks of 128 s each.
// ---------------------------------------------------------------------------
__global__ __launch_bounds__(256) void k_qk(const float* __restrict__ Q,
                                            const float* __restrict__ K,
                                            float* __restrict__ QK) {
    int b = blockIdx.x;
    int ch = b & 15;
    int th = b >> 4;
    int t = th / H_;
    int h = th % H_;
    int d = threadIdx.x & 63;
    int sg = threadIdx.x >> 6;
    const float* qb = Q + (size_t)t * SD_ + h * HD_ + d;
    const float* kb = K + (size_t)t * SD_ + h * HD_ + d;
    int s0 = ch * 128;
    float acc = 0.f;
    for (int s = s0 + sg; s < s0 + 128; s += 4)
        acc += qb[(size_t)s * D_] * kb[(size_t)s * D_];
    __shared__ float part[4][64];
    part[sg][d] = acc;
    __syncthreads();
    if (sg == 0) {
        float r = part[0][d] + part[1][d] + part[2][d] + part[3][d];
        atomicAdd(&QK[t * D_ + h * HD_ + d], r);
    }
}

// ---------------------------------------------------------------------------
// 5) if_node over T on QK (exact integers). Single block.
// ---------------------------------------------------------------------------
__global__ __launch_bounds__(768) void k_if_qk(const float* __restrict__ QK,
                                               float* __restrict__ QKs) {
    int j = threadIdx.x;
    if (j >= D_) return;
    float v = 0.f;
#pragma unroll
    for (int t = 0; t < T_; t++) {
        v += QK[t * D_ + j];
        float sp = (v >= 1.0f) ? 1.0f : 0.0f;
        QKs[t * D_ + j] = sp;
        if (sp > 0.f) v = 0.f;
    }
}

// ---------------------------------------------------------------------------
// 6) A[t,s,d] = V[t,s,d] * QKs[t,d]   (binary, exact)
// ---------------------------------------------------------------------------
__global__ __launch_bounds__(256) void k_form(const float* __restrict__ V,
                                              const float* __restrict__ QKs,
                                              float* __restrict__ A) {
    int i = blockIdx.x * blockDim.x + threadIdx.x;
    int idx = i * 4;
    if (idx >= TSD_) return;
    int t = idx / SD_;
    int d = idx % D_;
    float4 v = *(const float4*)(V + idx);
    float4 q = *(const float4*)(QKs + t * D_ + d);
    float4 o;
    o.x = v.x * q.x; o.y = v.y * q.y; o.z = v.z * q.z; o.w = v.w * q.w;
    *(float4*)(A + idx) = o;
}

// ---------------------------------------------------------------------------
// 7) Final BatchNorm1d (fp64 stats), writes fp32 to d_out.
// ---------------------------------------------------------------------------
__global__ __launch_bounds__(256) void k_bn_out(const float* __restrict__ Xin,
                                                float* __restrict__ out) {
    int s = blockIdx.x;
    __shared__ float buf[T_][D_];
    __shared__ double red[16];
    int tid = threadIdx.x;
    double sum = 0.0, sumsq = 0.0;
#pragma unroll
    for (int t = 0; t < T_; t++) {
        for (int d = tid; d < D_; d += 256) {
            float v = Xin[(size_t)t * SD_ + (size_t)s * D_ + d];
            buf[t][d] = v;
            double dv = (double)v;
            sum += dv;
            sumsq += dv * dv;
        }
    }
#pragma unroll
    for (int off = 32; off > 0; off >>= 1) {
        sum += __shfl_down(sum, off);
        sumsq += __shfl_down(sumsq, off);
    }
    int lane = tid & 63, wv = tid >> 6;
    if (lane == 0) { red[wv] = sum; red[4 + wv] = sumsq; }
    __syncthreads();
    if (tid == 0) {
        double s4 = red[0] + red[1] + red[2] + red[3];
        double q4 = red[4] + red[5] + red[6] + red[7];
        double mean = s4 / 3072.0;
        double var = q4 / 3072.0 - mean * mean;
        red[8] = mean;
        red[9] = 1.0 / sqrt(var + 1e-5);
    }
    __syncthreads();
    double mean = red[8], rstd = red[9];
    for (int d = tid; d < D_; d += 256) {
#pragma unroll
        for (int t = 0; t < T_; t++) {
            double v = (double)buf[t][d];
            out[(size_t)t * SD_ + (size_t)s * D_ + d] =
                (float)((v - mean) * rstd);
        }
    }
}

// ---------------------------------------------------------------------------
extern "C" void kernel_launch(void* const* d_in, const int* in_sizes, int n_in,
                              void* d_out, int out_size, void* d_ws,
                              size_t ws_size, hipStream_t stream) {
    const float* x  = (const float*)d_in[0];
    const float* wq = (const float*)d_in[1];
    const float* wk = (const float*)d_in[2];
    const float* wv = (const float*)d_in[3];
    const float* wo = (const float*)d_in[4];
    float* out = (float*)d_out;

    float* ws  = (float*)d_ws;
    float* tmp = ws;                    // spikes(x), later reused as QKV A-matrix
    float* Q   = ws + (size_t)TSD_;     // later reused as pre-BN output
    float* Kb  = ws + (size_t)2 * TSD_;
    float* V   = ws + (size_t)3 * TSD_;
    float* QK  = ws + (size_t)4 * TSD_;
    float* QKs = QK + T_ * D_;

    // 0) zero the QK accumulator (workspace is poisoned 0xAA)
    hipMemsetAsync(QK, 0, T_ * D_ * sizeof(float), stream);
    // 1) init spikes
    k_ifnode_x<<<SD_ / (4 * 256), 256, 0, stream>>>(x, tmp);
    // 2) Q/K/V GEMMs (share A in grid.z)
    k_gemm<<<dim3((T_ * S_) / BM, D_ / BN, 3), 256, 0, stream>>>(
        tmp, wq, wk, wv, Q, Kb, V, T_ * S_, D_, D_);
    // 3) BN + IF on Q, K, V (in place)
    k_bn_if<<<dim3(S_, 3), 256, 0, stream>>>(Q, Kb, V);
    // 4) talking-heads reduce over S (exact integer atomics)
    k_qk<<<T_ * H_ * 16, 256, 0, stream>>>(Q, Kb, QK);
    // 5) IF on QK
    k_if_qk<<<1, 768, 0, stream>>>(QK, QKs);
    // 6) QKV = V * QKs (broadcast) -> tmp
    k_form<<<TSD_ / (4 * 256), 256, 0, stream>>>(V, QKs, tmp);
    // 7) out_pre = QKV @ wo -> Q buffer
    k_gemm<<<dim3((T_ * S_) / BM, D_ / BN, 1), 256, 0, stream>>>(
        tmp, wo, wo, wo, Q, Q, Q, T_ * S_, D_, D_);
    // 8) final BN -> d_out
    k_bn_out<<<S_, 256, 0, stream>>>(Q, out);
}

// Round 3
// 294.924 us; speedup vs baseline: 3.3075x; 3.3075x over previous
//
#include <hip/hip_runtime.h>

#define T_ 4
#define S_ 2048
#define D_ 768
#define SD_ (S_ * D_)          // 1572864
#define TSD_ (T_ * SD_)        // 6291456
#define H_ 12
#define HD_ 64
#define PLANE_BYTES 2359296u   // 4 planes * 768 * 768 int8 per weight matrix

typedef int int32x4 __attribute__((ext_vector_type(4)));

// ---------------------------------------------------------------------------
// 0) Pack weights: wi = rint(w*2^30); balanced base-256 digits c0..c3 (int8);
//    store in MFMA B-fragment order: byte addr =
//      (((p*48 + nbg)*12 + kb)*64 + lane)*16 + j,  holding B[k][n] with
//      n = nbg*16 + (lane&15), k = kb*64 + (lane>>4)*16 + j.
//    blockIdx.y selects matrix (wq, wk, wv, wo).
// ---------------------------------------------------------------------------
__global__ __launch_bounds__(256) void k_prep_w(const float* __restrict__ wq,
                                                const float* __restrict__ wk,
                                                const float* __restrict__ wv,
                                                const float* __restrict__ wo,
                                                unsigned char* __restrict__ Bp) {
    const float* W = (blockIdx.y == 0) ? wq : (blockIdx.y == 1) ? wk
                   : (blockIdx.y == 2) ? wv : wo;
    unsigned char* out = Bp + (size_t)blockIdx.y * PLANE_BYTES;
    int idx = blockIdx.x * 256 + threadIdx.x;      // dword id, < 589824
    int j0 = idx & 3;
    int lane = (idx >> 2) & 63;
    int kb = (idx >> 8) % 12;
    int rest = (idx >> 8) / 12;
    int nbg = rest % 48;
    int p = rest / 48;                              // uniform per block
    int n = nbg * 16 + (lane & 15);
    int kbase = kb * 64 + (lane >> 4) * 16 + j0 * 4;
    unsigned int packed = 0;
#pragma unroll
    for (int jj = 0; jj < 4; jj++) {
        float w = W[(size_t)(kbase + jj) * D_ + n];
        int u = (int)rintf(w * 1073741824.0f);      // w * 2^30, |.| < 2^28
        for (int i = 0; i < p; i++) u = (u + 128) >> 8;  // peel lower digits
        packed |= ((unsigned int)(u & 255)) << (8 * jj);
    }
    *(unsigned int*)(out + (size_t)idx * 4) = packed;
}

// ---------------------------------------------------------------------------
// 1) if_node over x -> int8 spikes (fp64 membrane, bit-exact scan).
// ---------------------------------------------------------------------------
__global__ __launch_bounds__(256) void k_ifnode_x(const float* __restrict__ x,
                                                  unsigned char* __restrict__ As) {
    int i = blockIdx.x * blockDim.x + threadIdx.x;
    int idx = i * 4;
    if (idx >= SD_) return;
    double v[4] = {0.0, 0.0, 0.0, 0.0};
#pragma unroll
    for (int t = 0; t < T_; t++) {
        float4 xt = *(const float4*)(x + (size_t)t * SD_ + idx);
        float xs[4] = {xt.x, xt.y, xt.z, xt.w};
        uchar4 sp;
        unsigned char* so = &sp.x;
#pragma unroll
        for (int j = 0; j < 4; j++) {
            v[j] += (double)xs[j];
            unsigned char s = (v[j] >= 1.0) ? 1 : 0;
            so[j] = s;
            if (s) v[j] = 0.0;
        }
        *(uchar4*)(As + (size_t)t * SD_ + idx) = sp;
    }
}

// ---------------------------------------------------------------------------
// 2) i8 MFMA GEMM, exact fixed-point. C(fp32) = (A{0,1} . wi) * 2^-30.
//    Block 512 thr = 8 waves, tile 128(M) x 64(N); wave tile 32x32
//    (2x2 blocks of 16x16, 4 digit planes each). No LDS: A and B fragments
//    load straight from global (B n-tiles are L2-resident).
// ---------------------------------------------------------------------------
__global__ __launch_bounds__(512) void k_gemm_i8(
    const unsigned char* __restrict__ A,   // [M][768] spikes
    const unsigned char* __restrict__ Bp,  // packed digit planes
    float* __restrict__ C0, float* __restrict__ C1, float* __restrict__ C2,
    int bzoff) {
    int z = blockIdx.z;
    const unsigned char* B = Bp + (size_t)(bzoff + z) * PLANE_BYTES;
    float* C = (z == 0) ? C0 : (z == 1) ? C1 : C2;

    int tid = threadIdx.x;
    int lane = tid & 63;
    int wave = tid >> 6;              // 0..7
    int wm = wave >> 1;               // 0..3
    int wn = wave & 1;                // 0..1
    int m0 = blockIdx.x * 128 + wm * 32;
    int n0 = blockIdx.y * 64 + wn * 32;
    int row = lane & 15;
    int quad = lane >> 4;

    int32x4 zerov = {0, 0, 0, 0};
    int32x4 acc[2][2][4];
#pragma unroll
    for (int mb = 0; mb < 2; mb++)
#pragma unroll
        for (int nb = 0; nb < 2; nb++)
#pragma unroll
            for (int p = 0; p < 4; p++) acc[mb][nb][p] = zerov;

    const unsigned char* Aptr = A + (size_t)(m0 + row) * D_ + quad * 16;
    int nbg0 = n0 >> 4;

    for (int kb = 0; kb < 12; kb++) {
        int32x4 a0 = *(const int32x4*)(Aptr + kb * 64);
        int32x4 a1 = *(const int32x4*)(Aptr + (size_t)16 * D_ + kb * 64);
        int32x4 bf[2][4];
#pragma unroll
        for (int nb = 0; nb < 2; nb++)
#pragma unroll
            for (int p = 0; p < 4; p++)
                bf[nb][p] = *(const int32x4*)(
                    B + ((size_t)((p * 48 + nbg0 + nb) * 12 + kb) * 64 + lane) * 16);
#pragma unroll
        for (int nb = 0; nb < 2; nb++)
#pragma unroll
            for (int p = 0; p < 4; p++) {
                acc[0][nb][p] = __builtin_amdgcn_mfma_i32_16x16x64_i8(
                    a0, bf[nb][p], acc[0][nb][p], 0, 0, 0);
                acc[1][nb][p] = __builtin_amdgcn_mfma_i32_16x16x64_i8(
                    a1, bf[nb][p], acc[1][nb][p], 0, 0, 0);
            }
    }

#pragma unroll
    for (int mb = 0; mb < 2; mb++)
#pragma unroll
        for (int nb = 0; nb < 2; nb++)
#pragma unroll
            for (int r = 0; r < 4; r++) {
                long t = (long)acc[mb][nb][0][r] + ((long)acc[mb][nb][1][r] << 8)
                       + ((long)acc[mb][nb][2][r] << 16)
                       + ((long)acc[mb][nb][3][r] << 24);
                float v = (float)((double)t * (1.0 / 1073741824.0));
                int rr = m0 + mb * 16 + quad * 4 + r;   // C/D: row=quad*4+reg
                int cc = n0 + nb * 16 + row;            //      col=lane&15
                C[(size_t)rr * D_ + cc] = v;
            }
}

// ---------------------------------------------------------------------------
// 3) Fused BatchNorm1d (fp64 stats over T x D) + if_node (fp64). Q/K spikes
//    written fp32 in place; V spikes written int8 into As (A of GEMM2).
// ---------------------------------------------------------------------------
__global__ __launch_bounds__(256) void k_bn_if(float* __restrict__ Q,
                                               float* __restrict__ Kt,
                                               float* __restrict__ Vf,
                                               unsigned char* __restrict__ Vs) {
    int s = blockIdx.x;
    int y = blockIdx.y;
    float* X = (y == 0) ? Q : (y == 1) ? Kt : Vf;

    __shared__ float buf[T_][D_];
    __shared__ double red[16];

    int tid = threadIdx.x;
    double sum = 0.0, sumsq = 0.0;
#pragma unroll
    for (int t = 0; t < T_; t++) {
        for (int d = tid; d < D_; d += 256) {
            float v = X[(size_t)t * SD_ + (size_t)s * D_ + d];
            buf[t][d] = v;
            double dv = (double)v;
            sum += dv;
            sumsq += dv * dv;
        }
    }
#pragma unroll
    for (int off = 32; off > 0; off >>= 1) {
        sum += __shfl_down(sum, off);
        sumsq += __shfl_down(sumsq, off);
    }
    int lane = tid & 63, wv = tid >> 6;
    if (lane == 0) { red[wv] = sum; red[4 + wv] = sumsq; }
    __syncthreads();
    if (tid == 0) {
        double s4 = red[0] + red[1] + red[2] + red[3];
        double q4 = red[4] + red[5] + red[6] + red[7];
        double mean = s4 / 3072.0;
        double var = q4 / 3072.0 - mean * mean;
        red[8] = mean;
        red[9] = 1.0 / sqrt(var + 1e-5);
    }
    __syncthreads();
    double mean = red[8], rstd = red[9];
    for (int d = tid; d < D_; d += 256) {
        double v = 0.0;
#pragma unroll
        for (int t = 0; t < T_; t++) {
            double xn = ((double)buf[t][d] - mean) * rstd;
            v += xn;
            int sp = (v >= 1.0) ? 1 : 0;
            if (y == 2)
                Vs[(size_t)t * SD_ + (size_t)s * D_ + d] = (unsigned char)sp;
            else
                X[(size_t)t * SD_ + (size_t)s * D_ + d] = (float)sp;
            if (sp) v = 0.0;
        }
    }
}

// ---------------------------------------------------------------------------
// 4) QK[t,h,d] += sum_{s chunk} Q*K (binary -> exact integer fp32 atomics).
// ---------------------------------------------------------------------------
__global__ __launch_bounds__(256) void k_qk(const float* __restrict__ Q,
                                            const float* __restrict__ K,
                                            float* __restrict__ QK) {
    int b = blockIdx.x;
    int ch = b & 15;
    int th = b >> 4;
    int t = th / H_;
    int h = th % H_;
    int d = threadIdx.x & 63;
    int sg = threadIdx.x >> 6;
    const float* qb = Q + (size_t)t * SD_ + h * HD_ + d;
    const float* kb = K + (size_t)t * SD_ + h * HD_ + d;
    int s0 = ch * 128;
    float acc = 0.f;
    for (int s = s0 + sg; s < s0 + 128; s += 4)
        acc += qb[(size_t)s * D_] * kb[(size_t)s * D_];
    __shared__ float part[4][64];
    part[sg][d] = acc;
    __syncthreads();
    if (sg == 0) {
        float r = part[0][d] + part[1][d] + part[2][d] + part[3][d];
        atomicAdd(&QK[t * D_ + h * HD_ + d], r);
    }
}

// ---------------------------------------------------------------------------
// 5) if_node over T on QK (exact integers). Single block.
// ---------------------------------------------------------------------------
__global__ __launch_bounds__(768) void k_if_qk(const float* __restrict__ QK,
                                               float* __restrict__ QKs) {
    int j = threadIdx.x;
    if (j >= D_) return;
    float v = 0.f;
#pragma unroll
    for (int t = 0; t < T_; t++) {
        v += QK[t * D_ + j];
        float sp = (v >= 1.0f) ? 1.0f : 0.0f;
        QKs[t * D_ + j] = sp;
        if (sp > 0.f) v = 0.f;
    }
}

// ---------------------------------------------------------------------------
// 6) As[t,s,d] = Vspike & (QKs[t,d] != 0)   (in-place int8, exact)
// ---------------------------------------------------------------------------
__global__ __launch_bounds__(256) void k_form(const float* __restrict__ QKs,
                                              unsigned char* __restrict__ As) {
    int i = blockIdx.x * blockDim.x + threadIdx.x;
    int idx = i * 4;
    if (idx >= TSD_) return;
    int t = idx / SD_;
    int d = idx % D_;
    uchar4 a = *(const uchar4*)(As + idx);
    float4 q = *(const float4*)(QKs + t * D_ + d);
    a.x = (q.x > 0.f) ? a.x : 0;
    a.y = (q.y > 0.f) ? a.y : 0;
    a.z = (q.z > 0.f) ? a.z : 0;
    a.w = (q.w > 0.f) ? a.w : 0;
    *(uchar4*)(As + idx) = a;
}

// ---------------------------------------------------------------------------
// 7) Final BatchNorm1d (fp64 stats), writes fp32 to d_out.
// ---------------------------------------------------------------------------
__global__ __launch_bounds__(256) void k_bn_out(const float* __restrict__ Xin,
                                                float* __restrict__ out) {
    int s = blockIdx.x;
    __shared__ float buf[T_][D_];
    __shared__ double red[16];
    int tid = threadIdx.x;
    double sum = 0.0, sumsq = 0.0;
#pragma unroll
    for (int t = 0; t < T_; t++) {
        for (int d = tid; d < D_; d += 256) {
            float v = Xin[(size_t)t * SD_ + (size_t)s * D_ + d];
            buf[t][d] = v;
            double dv = (double)v;
            sum += dv;
            sumsq += dv * dv;
        }
    }
#pragma unroll
    for (int off = 32; off > 0; off >>= 1) {
        sum += __shfl_down(sum, off);
        sumsq += __shfl_down(sumsq, off);
    }
    int lane = tid & 63, wv = tid >> 6;
    if (lane == 0) { red[wv] = sum; red[4 + wv] = sumsq; }
    __syncthreads();
    if (tid == 0) {
        double s4 = red[0] + red[1] + red[2] + red[3];
        double q4 = red[4] + red[5] + red[6] + red[7];
        double mean = s4 / 3072.0;
        double var = q4 / 3072.0 - mean * mean;
        red[8] = mean;
        red[9] = 1.0 / sqrt(var + 1e-5);
    }
    __syncthreads();
    double mean = red[8], rstd = red[9];
    for (int d = tid; d < D_; d += 256) {
#pragma unroll
        for (int t = 0; t < T_; t++) {
            double v = (double)buf[t][d];
            out[(size_t)t * SD_ + (size_t)s * D_ + d] =
                (float)((v - mean) * rstd);
        }
    }
}

// ---------------------------------------------------------------------------
extern "C" void kernel_launch(void* const* d_in, const int* in_sizes, int n_in,
                              void* d_out, int out_size, void* d_ws,
                              size_t ws_size, hipStream_t stream) {
    const float* x  = (const float*)d_in[0];
    const float* wq = (const float*)d_in[1];
    const float* wk = (const float*)d_in[2];
    const float* wv = (const float*)d_in[3];
    const float* wo = (const float*)d_in[4];
    float* out = (float*)d_out;

    float* ws  = (float*)d_ws;
    float* Qf  = ws;                         // pre-BN Q, then GEMM2 out
    float* Kf  = ws + (size_t)TSD_;
    float* Vf  = ws + (size_t)2 * TSD_;
    float* QK  = ws + (size_t)3 * TSD_;      // 3072 floats
    float* QKs = QK + T_ * D_;
    unsigned char* As = (unsigned char*)(QKs + T_ * D_);  // int8 spikes, 6.3 MB
    unsigned char* Bp = As + (size_t)TSD_;                // packed weights, 9.4 MB

    // 0) zero QK accumulator; pack all 4 weight matrices
    hipMemsetAsync(QK, 0, T_ * D_ * sizeof(float), stream);
    k_prep_w<<<dim3(589824 / 256, 4), 256, 0, stream>>>(wq, wk, wv, wo, Bp);
    // 1) init spikes (int8)
    k_ifnode_x<<<SD_ / (4 * 256), 256, 0, stream>>>(x, As);
    // 2) Q/K/V GEMMs on matrix cores (exact fixed-point)
    k_gemm_i8<<<dim3(64, 12, 3), 512, 0, stream>>>(As, Bp, Qf, Kf, Vf, 0);
    // 3) BN + IF; Q/K spikes fp32 in place, V spikes int8 -> As
    k_bn_if<<<dim3(S_, 3), 256, 0, stream>>>(Qf, Kf, Vf, As);
    // 4) talking-heads reduce over S
    k_qk<<<T_ * H_ * 16, 256, 0, stream>>>(Qf, Kf, QK);
    // 5) IF on QK
    k_if_qk<<<1, 768, 0, stream>>>(QK, QKs);
    // 6) QKV spikes = Vspike & QKspike -> As (in place)
    k_form<<<TSD_ / (4 * 256), 256, 0, stream>>>(QKs, As);
    // 7) out_pre = QKV @ wo -> Qf
    k_gemm_i8<<<dim3(64, 12, 1), 512, 0, stream>>>(As, Bp, Qf, Qf, Qf, 3);
    // 8) final BN -> d_out
    k_bn_out<<<S_, 256, 0, stream>>>(Qf, out);
}

// Round 4
// 240.941 us; speedup vs baseline: 4.0486x; 1.2241x over previous
//
#include <hip/hip_runtime.h>

#define T_ 4
#define S_ 2048
#define D_ 768
#define SD_ (S_ * D_)          // 1572864
#define TSD_ (T_ * SD_)        // 6291456
#define H_ 12
#define HD_ 64
#define PLANE_BYTES 2359296u   // 4 planes * 768 * 768 int8 per weight matrix

typedef int int32x4 __attribute__((ext_vector_type(4)));

// async global->LDS, 16B per lane; LDS dest = base + lane*16 (wave-uniform base)
__device__ __forceinline__ void cp16(unsigned char* lds, const unsigned char* g) {
    __builtin_amdgcn_global_load_lds(
        (const __attribute__((address_space(1))) unsigned int*)g,
        (__attribute__((address_space(3))) unsigned int*)lds, 16, 0, 0);
}

// ---------------------------------------------------------------------------
// 0) Pack weights: wi = rint(w*2^30); base-256 digits c0..c3 (int8);
//    B-fragment order: byte addr = (((p*48 + nbg)*12 + kb)*64 + lane)*16 + j,
//    holding B[k][n], n = nbg*16 + (lane&15), k = kb*64 + (lane>>4)*16 + j.
// ---------------------------------------------------------------------------
__global__ __launch_bounds__(256) void k_prep_w(const float* __restrict__ wq,
                                                const float* __restrict__ wk,
                                                const float* __restrict__ wv,
                                                const float* __restrict__ wo,
                                                unsigned char* __restrict__ Bp) {
    const float* W = (blockIdx.y == 0) ? wq : (blockIdx.y == 1) ? wk
                   : (blockIdx.y == 2) ? wv : wo;
    unsigned char* out = Bp + (size_t)blockIdx.y * PLANE_BYTES;
    int idx = blockIdx.x * 256 + threadIdx.x;      // dword id, < 589824
    int j0 = idx & 3;
    int lane = (idx >> 2) & 63;
    int kb = (idx >> 8) % 12;
    int rest = (idx >> 8) / 12;
    int nbg = rest % 48;
    int p = rest / 48;
    int n = nbg * 16 + (lane & 15);
    int kbase = kb * 64 + (lane >> 4) * 16 + j0 * 4;
    unsigned int packed = 0;
#pragma unroll
    for (int jj = 0; jj < 4; jj++) {
        float w = W[(size_t)(kbase + jj) * D_ + n];
        int u = (int)rintf(w * 1073741824.0f);      // w * 2^30, |.| < 2^28
        for (int i = 0; i < p; i++) u = (u + 128) >> 8;  // peel lower digits
        packed |= ((unsigned int)(u & 255)) << (8 * jj);
    }
    *(unsigned int*)(out + (size_t)idx * 4) = packed;
}

// ---------------------------------------------------------------------------
// 1) if_node over x -> int8 spikes (fp64 membrane, bit-exact scan).
// ---------------------------------------------------------------------------
__global__ __launch_bounds__(256) void k_ifnode_x(const float* __restrict__ x,
                                                  unsigned char* __restrict__ As) {
    int i = blockIdx.x * blockDim.x + threadIdx.x;
    int idx = i * 4;
    if (idx >= SD_) return;
    double v[4] = {0.0, 0.0, 0.0, 0.0};
#pragma unroll
    for (int t = 0; t < T_; t++) {
        float4 xt = *(const float4*)(x + (size_t)t * SD_ + idx);
        float xs[4] = {xt.x, xt.y, xt.z, xt.w};
        uchar4 sp;
        unsigned char* so = &sp.x;
#pragma unroll
        for (int j = 0; j < 4; j++) {
            v[j] += (double)xs[j];
            unsigned char s = (v[j] >= 1.0) ? 1 : 0;
            so[j] = s;
            if (s) v[j] = 0.0;
        }
        *(uchar4*)(As + (size_t)t * SD_ + idx) = sp;
    }
}

// ---------------------------------------------------------------------------
// 2) i8 MFMA GEMM, exact fixed-point, LDS double-buffered.
//    Block 256 thr = 4 waves. Tile M=128, N=64. Wave tile 32(M) x 64(N) x 4p.
//    Per kstep (K=64 bytes): A stage 8KB (8 x 1KB chunks), B stage 16KB
//    (16 x 1KB fragment chunks), via global_load_lds width=16.
// ---------------------------------------------------------------------------
#define LDSBUF 24576

__global__ __launch_bounds__(256, 2) void k_gemm_i8(
    const unsigned char* __restrict__ A,   // [M][768] spikes
    const unsigned char* __restrict__ Bp,  // packed digit planes
    float* __restrict__ C0, float* __restrict__ C1, float* __restrict__ C2,
    int bzoff) {
    int z = blockIdx.z;
    const unsigned char* B = Bp + (size_t)(bzoff + z) * PLANE_BYTES;
    float* C = (z == 0) ? C0 : (z == 1) ? C1 : C2;

    __shared__ __align__(16) unsigned char smem[2 * LDSBUF];

    int tid = threadIdx.x;
    int lane = tid & 63;
    int w = tid >> 6;                 // wave 0..3
    int row0 = blockIdx.x * 128;
    int n0 = blockIdx.y * 64;
    int nbg0 = blockIdx.y * 4;
    int col = lane & 15;
    int quad = lane >> 4;

    int32x4 zerov = {0, 0, 0, 0};
    int32x4 acc[2][4][4];             // [mb][nb][p]
#pragma unroll
    for (int mb = 0; mb < 2; mb++)
#pragma unroll
        for (int nb = 0; nb < 4; nb++)
#pragma unroll
            for (int p = 0; p < 4; p++) acc[mb][nb][p] = zerov;

    // staging source addresses (per wave: 2 A chunks + 4 B chunks)
    const unsigned char* gA0 = A + (size_t)(row0 + (2 * w) * 16 + (lane >> 2)) * D_
                                 + (lane & 3) * 16;
    const unsigned char* gA1 = gA0 + (size_t)16 * D_;

    auto stage = [&](int buf, int kb) {
        unsigned char* ab = smem + buf * LDSBUF;
        cp16(ab + (2 * w + 0) * 1024, gA0 + kb * 64);
        cp16(ab + (2 * w + 1) * 1024, gA1 + kb * 64);
        unsigned char* bb = ab + 8192;
#pragma unroll
        for (int qi = 0; qi < 4; qi++) {
            int q = 4 * w + qi;           // chunk id: p = q>>2, nb = q&3
            int p = q >> 2, nb = q & 3;
            const unsigned char* gB =
                B + ((size_t)((p * 48 + nbg0 + nb) * 12 + kb) * 64 + lane) * 16;
            cp16(bb + q * 1024, gB);
        }
    };

    stage(0, 0);
    __syncthreads();

    for (int kb = 0; kb < 12; kb++) {
        int cur = kb & 1;
        if (kb < 11) stage(1 - cur, kb + 1);
        const unsigned char* ab = smem + cur * LDSBUF;
        int32x4 a0 = *(const int32x4*)(ab + (w * 32 + col) * 64 + quad * 16);
        int32x4 a1 = *(const int32x4*)(ab + (w * 32 + 16 + col) * 64 + quad * 16);
        const unsigned char* bb = ab + 8192;
#pragma unroll
        for (int p = 0; p < 4; p++)
#pragma unroll
            for (int nb = 0; nb < 4; nb++) {
                int32x4 bf = *(const int32x4*)(bb + ((p * 4 + nb) * 64 + lane) * 16);
                acc[0][nb][p] = __builtin_amdgcn_mfma_i32_16x16x64_i8(
                    a0, bf, acc[0][nb][p], 0, 0, 0);
                acc[1][nb][p] = __builtin_amdgcn_mfma_i32_16x16x64_i8(
                    a1, bf, acc[1][nb][p], 0, 0, 0);
            }
        __syncthreads();
    }

#pragma unroll
    for (int mb = 0; mb < 2; mb++)
#pragma unroll
        for (int nb = 0; nb < 4; nb++)
#pragma unroll
            for (int r = 0; r < 4; r++) {
                long t = (long)acc[mb][nb][0][r] + ((long)acc[mb][nb][1][r] << 8)
                       + ((long)acc[mb][nb][2][r] << 16)
                       + ((long)acc[mb][nb][3][r] << 24);
                float v = (float)((double)t * (1.0 / 1073741824.0));
                int rr = row0 + w * 32 + mb * 16 + quad * 4 + r;
                int cc = n0 + nb * 16 + col;
                C[(size_t)rr * D_ + cc] = v;
            }
}

// ---------------------------------------------------------------------------
// 3) Fused BatchNorm1d (fp64 stats over T x D) + if_node (fp64). Q/K spikes
//    written fp32 in place; V spikes written int8 into As.
// ---------------------------------------------------------------------------
__global__ __launch_bounds__(256) void k_bn_if(float* __restrict__ Q,
                                               float* __restrict__ Kt,
                                               float* __restrict__ Vf,
                                               unsigned char* __restrict__ Vs) {
    int s = blockIdx.x;
    int y = blockIdx.y;
    float* X = (y == 0) ? Q : (y == 1) ? Kt : Vf;

    __shared__ float buf[T_][D_];
    __shared__ double red[16];

    int tid = threadIdx.x;
    double sum = 0.0, sumsq = 0.0;
#pragma unroll
    for (int t = 0; t < T_; t++) {
        for (int d = tid; d < D_; d += 256) {
            float v = X[(size_t)t * SD_ + (size_t)s * D_ + d];
            buf[t][d] = v;
            double dv = (double)v;
            sum += dv;
            sumsq += dv * dv;
        }
    }
#pragma unroll
    for (int off = 32; off > 0; off >>= 1) {
        sum += __shfl_down(sum, off);
        sumsq += __shfl_down(sumsq, off);
    }
    int lane = tid & 63, wv = tid >> 6;
    if (lane == 0) { red[wv] = sum; red[4 + wv] = sumsq; }
    __syncthreads();
    if (tid == 0) {
        double s4 = red[0] + red[1] + red[2] + red[3];
        double q4 = red[4] + red[5] + red[6] + red[7];
        double mean = s4 / 3072.0;
        double var = q4 / 3072.0 - mean * mean;
        red[8] = mean;
        red[9] = 1.0 / sqrt(var + 1e-5);
    }
    __syncthreads();
    double mean = red[8], rstd = red[9];
    for (int d = tid; d < D_; d += 256) {
        double v = 0.0;
#pragma unroll
        for (int t = 0; t < T_; t++) {
            double xn = ((double)buf[t][d] - mean) * rstd;
            v += xn;
            int sp = (v >= 1.0) ? 1 : 0;
            if (y == 2)
                Vs[(size_t)t * SD_ + (size_t)s * D_ + d] = (unsigned char)sp;
            else
                X[(size_t)t * SD_ + (size_t)s * D_ + d] = (float)sp;
            if (sp) v = 0.0;
        }
    }
}

// ---------------------------------------------------------------------------
// 4) QK[t,h,d] += sum_{s chunk} Q*K (binary -> exact integer fp32 atomics).
// ---------------------------------------------------------------------------
__global__ __launch_bounds__(256) void k_qk(const float* __restrict__ Q,
                                            const float* __restrict__ K,
                                            float* __restrict__ QK) {
    int b = blockIdx.x;
    int ch = b & 15;
    int th = b >> 4;
    int t = th / H_;
    int h = th % H_;
    int d = threadIdx.x & 63;
    int sg = threadIdx.x >> 6;
    const float* qb = Q + (size_t)t * SD_ + h * HD_ + d;
    const float* kb = K + (size_t)t * SD_ + h * HD_ + d;
    int s0 = ch * 128;
    float acc = 0.f;
    for (int s = s0 + sg; s < s0 + 128; s += 4)
        acc += qb[(size_t)s * D_] * kb[(size_t)s * D_];
    __shared__ float part[4][64];
    part[sg][d] = acc;
    __syncthreads();
    if (sg == 0) {
        float r = part[0][d] + part[1][d] + part[2][d] + part[3][d];
        atomicAdd(&QK[t * D_ + h * HD_ + d], r);
    }
}

// ---------------------------------------------------------------------------
// 5) As[t,s,d] = Vspike & if_node(QK)[t,d]; IF scan recomputed inline from
//    QK (12 KB, L2-resident; exact integers).
// ---------------------------------------------------------------------------
__global__ __launch_bounds__(256) void k_form(const float* __restrict__ QK,
                                              unsigned char* __restrict__ As) {
    int i = blockIdx.x * 256 + threadIdx.x;
    int idx = i * 4;
    if (idx >= TSD_) return;
    int t = idx / SD_;
    int d = idx % D_;
    uchar4 a = *(const uchar4*)(As + idx);
    unsigned char* ap = &a.x;
#pragma unroll
    for (int j = 0; j < 4; j++) {
        float v = 0.f;
        float sp = 0.f;
        for (int tt = 0; tt <= t; tt++) {
            v += QK[tt * D_ + d + j];
            sp = (v >= 1.0f) ? 1.0f : 0.0f;
            if (sp > 0.f) v = 0.f;
        }
        ap[j] = (sp > 0.f) ? ap[j] : 0;
    }
    *(uchar4*)(As + idx) = a;
}

// ---------------------------------------------------------------------------
// 6) Final BatchNorm1d (fp64 stats), writes fp32 to d_out.
// ---------------------------------------------------------------------------
__global__ __launch_bounds__(256) void k_bn_out(const float* __restrict__ Xin,
                                                float* __restrict__ out) {
    int s = blockIdx.x;
    __shared__ float buf[T_][D_];
    __shared__ double red[16];
    int tid = threadIdx.x;
    double sum = 0.0, sumsq = 0.0;
#pragma unroll
    for (int t = 0; t < T_; t++) {
        for (int d = tid; d < D_; d += 256) {
            float v = Xin[(size_t)t * SD_ + (size_t)s * D_ + d];
            buf[t][d] = v;
            double dv = (double)v;
            sum += dv;
            sumsq += dv * dv;
        }
    }
#pragma unroll
    for (int off = 32; off > 0; off >>= 1) {
        sum += __shfl_down(sum, off);
        sumsq += __shfl_down(sumsq, off);
    }
    int lane = tid & 63, wv = tid >> 6;
    if (lane == 0) { red[wv] = sum; red[4 + wv] = sumsq; }
    __syncthreads();
    if (tid == 0) {
        double s4 = red[0] + red[1] + red[2] + red[3];
        double q4 = red[4] + red[5] + red[6] + red[7];
        double mean = s4 / 3072.0;
        double var = q4 / 3072.0 - mean * mean;
        red[8] = mean;
        red[9] = 1.0 / sqrt(var + 1e-5);
    }
    __syncthreads();
    double mean = red[8], rstd = red[9];
    for (int d = tid; d < D_; d += 256) {
#pragma unroll
        for (int t = 0; t < T_; t++) {
            double v = (double)buf[t][d];
            out[(size_t)t * SD_ + (size_t)s * D_ + d] =
                (float)((v - mean) * rstd);
        }
    }
}

// ---------------------------------------------------------------------------
extern "C" void kernel_launch(void* const* d_in, const int* in_sizes, int n_in,
                              void* d_out, int out_size, void* d_ws,
                              size_t ws_size, hipStream_t stream) {
    const float* x  = (const float*)d_in[0];
    const float* wq = (const float*)d_in[1];
    const float* wk = (const float*)d_in[2];
    const float* wv = (const float*)d_in[3];
    const float* wo = (const float*)d_in[4];
    float* out = (float*)d_out;

    float* ws  = (float*)d_ws;
    float* Qf  = ws;                         // pre-BN Q, then GEMM2 out
    float* Kf  = ws + (size_t)TSD_;
    float* Vf  = ws + (size_t)2 * TSD_;
    float* QK  = ws + (size_t)3 * TSD_;      // 3072 floats
    float* QKs = QK + T_ * D_;               // (slot kept for layout stability)
    unsigned char* As = (unsigned char*)(QKs + T_ * D_);  // int8 spikes
    unsigned char* Bp = As + (size_t)TSD_;                // packed weights

    // 0) zero QK accumulator; pack all 4 weight matrices
    hipMemsetAsync(QK, 0, T_ * D_ * sizeof(float), stream);
    k_prep_w<<<dim3(589824 / 256, 4), 256, 0, stream>>>(wq, wk, wv, wo, Bp);
    // 1) init spikes (int8)
    k_ifnode_x<<<SD_ / (4 * 256), 256, 0, stream>>>(x, As);
    // 2) Q/K/V GEMMs on matrix cores (exact fixed-point, LDS dbuf)
    k_gemm_i8<<<dim3(64, 12, 3), 256, 0, stream>>>(As, Bp, Qf, Kf, Vf, 0);
    // 3) BN + IF; Q/K spikes fp32 in place, V spikes int8 -> As
    k_bn_if<<<dim3(S_, 3), 256, 0, stream>>>(Qf, Kf, Vf, As);
    // 4) talking-heads reduce over S
    k_qk<<<T_ * H_ * 16, 256, 0, stream>>>(Qf, Kf, QK);
    // 5) QKV spikes = Vspike & if_node(QK) -> As (in place)
    k_form<<<TSD_ / (4 * 256), 256, 0, stream>>>(QK, As);
    // 6) out_pre = QKV @ wo -> Qf
    k_gemm_i8<<<dim3(64, 12, 1), 256, 0, stream>>>(As, Bp, Qf, Qf, Qf, 3);
    // 7) final BN -> d_out
    k_bn_out<<<S_, 256, 0, stream>>>(Qf, out);
}

// Round 5
// 227.975 us; speedup vs baseline: 4.2789x; 1.0569x over previous
//
#include <hip/hip_runtime.h>

#define T_ 4
#define S_ 2048
#define D_ 768
#define SD_ (S_ * D_)          // 1572864
#define TSD_ (T_ * SD_)        // 6291456
#define H_ 12
#define HD_ 64
#define PLANE_BYTES 2359296u   // 4 planes * 768 * 768 int8 per weight matrix

typedef int int32x4 __attribute__((ext_vector_type(4)));

// async global->LDS, 16B per lane; LDS dest = base + lane*16 (wave-uniform base)
__device__ __forceinline__ void cp16(unsigned char* lds, const unsigned char* g) {
    __builtin_amdgcn_global_load_lds(
        (const __attribute__((address_space(1))) unsigned int*)g,
        (__attribute__((address_space(3))) unsigned int*)lds, 16, 0, 0);
}

// ---------------------------------------------------------------------------
// 0) Pack weights: wi = rint(w*2^30); base-256 digits c0..c3 (int8);
//    B-fragment order: byte addr = (((p*48 + nbg)*12 + kb)*64 + lane)*16 + j,
//    holding B[k][n], n = nbg*16 + (lane&15), k = kb*64 + (lane>>4)*16 + j.
// ---------------------------------------------------------------------------
__global__ __launch_bounds__(256) void k_prep_w(const float* __restrict__ wq,
                                                const float* __restrict__ wk,
                                                const float* __restrict__ wv,
                                                const float* __restrict__ wo,
                                                unsigned char* __restrict__ Bp) {
    const float* W = (blockIdx.y == 0) ? wq : (blockIdx.y == 1) ? wk
                   : (blockIdx.y == 2) ? wv : wo;
    unsigned char* out = Bp + (size_t)blockIdx.y * PLANE_BYTES;
    int idx = blockIdx.x * 256 + threadIdx.x;      // dword id, < 589824
    int j0 = idx & 3;
    int lane = (idx >> 2) & 63;
    int kb = (idx >> 8) % 12;
    int rest = (idx >> 8) / 12;
    int nbg = rest % 48;
    int p = rest / 48;
    int n = nbg * 16 + (lane & 15);
    int kbase = kb * 64 + (lane >> 4) * 16 + j0 * 4;
    unsigned int packed = 0;
#pragma unroll
    for (int jj = 0; jj < 4; jj++) {
        float w = W[(size_t)(kbase + jj) * D_ + n];
        int u = (int)rintf(w * 1073741824.0f);      // w * 2^30, |.| < 2^28
        for (int i = 0; i < p; i++) u = (u + 128) >> 8;  // peel lower digits
        packed |= ((unsigned int)(u & 255)) << (8 * jj);
    }
    *(unsigned int*)(out + (size_t)idx * 4) = packed;
}

// ---------------------------------------------------------------------------
// 1) if_node over x -> int8 spikes (fp64 membrane, bit-exact scan).
// ---------------------------------------------------------------------------
__global__ __launch_bounds__(256) void k_ifnode_x(const float* __restrict__ x,
                                                  unsigned char* __restrict__ As) {
    int i = blockIdx.x * blockDim.x + threadIdx.x;
    int idx = i * 4;
    if (idx >= SD_) return;
    double v[4] = {0.0, 0.0, 0.0, 0.0};
#pragma unroll
    for (int t = 0; t < T_; t++) {
        float4 xt = *(const float4*)(x + (size_t)t * SD_ + idx);
        float xs[4] = {xt.x, xt.y, xt.z, xt.w};
        uchar4 sp;
        unsigned char* so = &sp.x;
#pragma unroll
        for (int j = 0; j < 4; j++) {
            v[j] += (double)xs[j];
            unsigned char s = (v[j] >= 1.0) ? 1 : 0;
            so[j] = s;
            if (s) v[j] = 0.0;
        }
        *(uchar4*)(As + (size_t)t * SD_ + idx) = sp;
    }
}

// ---------------------------------------------------------------------------
// 2) i8 MFMA GEMM, exact fixed-point, LDS double-buffered.
//    Block 256 thr = 4 waves in 2x2 (wm,wn). Tile M=128, N=64.
//    Wave tile 64M x 32N x 4 planes -> each A/B LDS frag read by 2 waves
//    (48KB LDS reads per block-kstep vs 653 cyc of MFMA issue).
//    Optional A-mask Ms[t][768] (QK spikes) ANDed in-register (k-only dep).
// ---------------------------------------------------------------------------
#define LDSBUF 24576

__global__ __launch_bounds__(256, 2) void k_gemm_i8(
    const unsigned char* __restrict__ A,   // [M][768] spikes
    const unsigned char* __restrict__ Bp,  // packed digit planes
    const unsigned char* __restrict__ Ms,  // mask [T][768] or nullptr
    float* __restrict__ C0, float* __restrict__ C1, float* __restrict__ C2,
    int bzoff) {
    int z = blockIdx.z;
    const unsigned char* B = Bp + (size_t)(bzoff + z) * PLANE_BYTES;
    float* C = (z == 0) ? C0 : (z == 1) ? C1 : C2;

    __shared__ __align__(16) unsigned char smem[2 * LDSBUF];

    int tid = threadIdx.x;
    int lane = tid & 63;
    int w = tid >> 6;                 // wave 0..3
    int wm = w >> 1;                  // 0..1
    int wn = w & 1;                   // 0..1
    int row0 = blockIdx.x * 128;
    int tI = row0 >> 11;              // uniform t for this block (2048 rows/t)
    int n0 = blockIdx.y * 64;
    int nbg0 = blockIdx.y * 4;
    int col = lane & 15;
    int quad = lane >> 4;

    int32x4 zerov = {0, 0, 0, 0};
    int32x4 acc[4][2][4];             // [mb][nb][p]
#pragma unroll
    for (int mb = 0; mb < 4; mb++)
#pragma unroll
        for (int nb = 0; nb < 2; nb++)
#pragma unroll
            for (int p = 0; p < 4; p++) acc[mb][nb][p] = zerov;

    // staging source addresses (per wave: 2 A chunks + 4 B chunks)
    const unsigned char* gA0 = A + (size_t)(row0 + (2 * w) * 16 + (lane >> 2)) * D_
                                 + (lane & 3) * 16;
    const unsigned char* gA1 = gA0 + (size_t)16 * D_;

    auto stage = [&](int buf, int kb) {
        unsigned char* ab = smem + buf * LDSBUF;
        cp16(ab + (2 * w + 0) * 1024, gA0 + kb * 64);
        cp16(ab + (2 * w + 1) * 1024, gA1 + kb * 64);
        unsigned char* bb = ab + 8192;
#pragma unroll
        for (int qi = 0; qi < 4; qi++) {
            int q = 4 * w + qi;           // chunk id: p = q>>2, nb = q&3
            int p = q >> 2, nb = q & 3;
            const unsigned char* gB =
                B + ((size_t)((p * 48 + nbg0 + nb) * 12 + kb) * 64 + lane) * 16;
            cp16(bb + q * 1024, gB);
        }
    };

    stage(0, 0);
    __syncthreads();

    for (int kb = 0; kb < 12; kb++) {
        int cur = kb & 1;
        if (kb < 11) stage(1 - cur, kb + 1);
        const unsigned char* ab = smem + cur * LDSBUF;
        int32x4 af[4];
#pragma unroll
        for (int mb = 0; mb < 4; mb++)
            af[mb] = *(const int32x4*)(
                ab + (wm * 64 + mb * 16 + col) * 64 + quad * 16);
        if (Ms) {
            int32x4 mv = *(const int32x4*)(Ms + tI * D_ + kb * 64 + quad * 16);
#pragma unroll
            for (int mb = 0; mb < 4; mb++) af[mb] &= mv;
        }
        const unsigned char* bb = ab + 8192;
#pragma unroll
        for (int p = 0; p < 4; p++)
#pragma unroll
            for (int nb = 0; nb < 2; nb++) {
                int32x4 bf = *(const int32x4*)(
                    bb + ((p * 4 + wn * 2 + nb) * 64 + lane) * 16);
#pragma unroll
                for (int mb = 0; mb < 4; mb++)
                    acc[mb][nb][p] = __builtin_amdgcn_mfma_i32_16x16x64_i8(
                        af[mb], bf, acc[mb][nb][p], 0, 0, 0);
            }
        __syncthreads();
    }

#pragma unroll
    for (int mb = 0; mb < 4; mb++)
#pragma unroll
        for (int nb = 0; nb < 2; nb++)
#pragma unroll
            for (int r = 0; r < 4; r++) {
                long t = (long)acc[mb][nb][0][r] + ((long)acc[mb][nb][1][r] << 8)
                       + ((long)acc[mb][nb][2][r] << 16)
                       + ((long)acc[mb][nb][3][r] << 24);
                float v = (float)((double)t * (1.0 / 1073741824.0));
                int rr = row0 + wm * 64 + mb * 16 + quad * 4 + r;
                int cc = n0 + wn * 32 + nb * 16 + col;
                C[(size_t)rr * D_ + cc] = v;
            }
}

// ---------------------------------------------------------------------------
// 3) Fused BatchNorm1d (fp64 stats over T x D) + if_node (fp64).
//    Reads fp32 GEMM outputs; writes int8 spikes to Qs/Ks/Vs.
// ---------------------------------------------------------------------------
__global__ __launch_bounds__(256) void k_bn_if(const float* __restrict__ Qf,
                                               const float* __restrict__ Kf,
                                               const float* __restrict__ Vf,
                                               unsigned char* __restrict__ Qs,
                                               unsigned char* __restrict__ Ks,
                                               unsigned char* __restrict__ Vs) {
    int s = blockIdx.x;
    int y = blockIdx.y;
    const float* X = (y == 0) ? Qf : (y == 1) ? Kf : Vf;
    unsigned char* Sp = (y == 0) ? Qs : (y == 1) ? Ks : Vs;

    __shared__ float buf[T_][D_];
    __shared__ double red[16];

    int tid = threadIdx.x;
    double sum = 0.0, sumsq = 0.0;
#pragma unroll
    for (int t = 0; t < T_; t++) {
        for (int d = tid; d < D_; d += 256) {
            float v = X[(size_t)t * SD_ + (size_t)s * D_ + d];
            buf[t][d] = v;
            double dv = (double)v;
            sum += dv;
            sumsq += dv * dv;
        }
    }
#pragma unroll
    for (int off = 32; off > 0; off >>= 1) {
        sum += __shfl_down(sum, off);
        sumsq += __shfl_down(sumsq, off);
    }
    int lane = tid & 63, wv = tid >> 6;
    if (lane == 0) { red[wv] = sum; red[4 + wv] = sumsq; }
    __syncthreads();
    if (tid == 0) {
        double s4 = red[0] + red[1] + red[2] + red[3];
        double q4 = red[4] + red[5] + red[6] + red[7];
        double mean = s4 / 3072.0;
        double var = q4 / 3072.0 - mean * mean;
        red[8] = mean;
        red[9] = 1.0 / sqrt(var + 1e-5);
    }
    __syncthreads();
    double mean = red[8], rstd = red[9];
    for (int d = tid; d < D_; d += 256) {
        double v = 0.0;
#pragma unroll
        for (int t = 0; t < T_; t++) {
            double xn = ((double)buf[t][d] - mean) * rstd;
            v += xn;
            int sp = (v >= 1.0) ? 1 : 0;
            Sp[(size_t)t * SD_ + (size_t)s * D_ + d] = (unsigned char)sp;
            if (sp) v = 0.0;
        }
    }
}

// ---------------------------------------------------------------------------
// 4) QK[t,h,d] += sum_{s chunk} q&k. int8 spikes; bytewise AND + byte-sums
//    (exact small integers), fp32 atomics of exact integers.
//    grid = T*H*16 chunks of 128 s. Thread: (dq = d-quad 0..15, sl = 0..15).
// ---------------------------------------------------------------------------
__global__ __launch_bounds__(256) void k_qk(const unsigned char* __restrict__ Qs,
                                            const unsigned char* __restrict__ Ks,
                                            float* __restrict__ QK) {
    int b = blockIdx.x;
    int ch = b & 15;
    int th = b >> 4;
    int t = th / H_;
    int h = th % H_;
    int dq = threadIdx.x & 15;
    int sl = threadIdx.x >> 4;
    const unsigned int* qb = (const unsigned int*)(Qs + (size_t)t * SD_ + h * HD_);
    const unsigned int* kb = (const unsigned int*)(Ks + (size_t)t * SD_ + h * HD_);
    int s0 = ch * 128;
    unsigned int acc = 0;                       // 4 byte-lanes, each <= 8
    for (int s = s0 + sl; s < s0 + 128; s += 16)
        acc += (qb[s * 192 + dq] & kb[s * 192 + dq]);
    __shared__ unsigned int part[16][16];
    part[sl][dq] = acc;
    __syncthreads();
    if (sl == 0) {
        unsigned int tot = 0;
#pragma unroll
        for (int i = 0; i < 16; i++) tot += part[i][dq];   // bytes <= 128
#pragma unroll
        for (int j = 0; j < 4; j++) {
            float v = (float)((tot >> (8 * j)) & 255u);
            atomicAdd(&QK[t * D_ + h * HD_ + dq * 4 + j], v);
        }
    }
}

// ---------------------------------------------------------------------------
// 5) if_node over T on QK (exact integers) -> int8 mask QKm[t][768].
// ---------------------------------------------------------------------------
__global__ __launch_bounds__(256) void k_if_qk(const float* __restrict__ QK,
                                               unsigned char* __restrict__ QKm) {
    int j = blockIdx.x * 256 + threadIdx.x;
    if (j >= D_) return;
    float v = 0.f;
#pragma unroll
    for (int t = 0; t < T_; t++) {
        v += QK[t * D_ + j];
        unsigned char sp = (v >= 1.0f) ? 1 : 0;
        QKm[t * D_ + j] = sp;
        if (sp) v = 0.f;
    }
}

// ---------------------------------------------------------------------------
// 6) Final BatchNorm1d (fp64 stats), writes fp32 to d_out.
// ---------------------------------------------------------------------------
__global__ __launch_bounds__(256) void k_bn_out(const float* __restrict__ Xin,
                                                float* __restrict__ out) {
    int s = blockIdx.x;
    __shared__ float buf[T_][D_];
    __shared__ double red[16];
    int tid = threadIdx.x;
    double sum = 0.0, sumsq = 0.0;
#pragma unroll
    for (int t = 0; t < T_; t++) {
        for (int d = tid; d < D_; d += 256) {
            float v = Xin[(size_t)t * SD_ + (size_t)s * D_ + d];
            buf[t][d] = v;
            double dv = (double)v;
            sum += dv;
            sumsq += dv * dv;
        }
    }
#pragma unroll
    for (int off = 32; off > 0; off >>= 1) {
        sum += __shfl_down(sum, off);
        sumsq += __shfl_down(sumsq, off);
    }
    int lane = tid & 63, wv = tid >> 6;
    if (lane == 0) { red[wv] = sum; red[4 + wv] = sumsq; }
    __syncthreads();
    if (tid == 0) {
        double s4 = red[0] + red[1] + red[2] + red[3];
        double q4 = red[4] + red[5] + red[6] + red[7];
        double mean = s4 / 3072.0;
        double var = q4 / 3072.0 - mean * mean;
        red[8] = mean;
        red[9] = 1.0 / sqrt(var + 1e-5);
    }
    __syncthreads();
    double mean = red[8], rstd = red[9];
    for (int d = tid; d < D_; d += 256) {
#pragma unroll
        for (int t = 0; t < T_; t++) {
            double v = (double)buf[t][d];
            out[(size_t)t * SD_ + (size_t)s * D_ + d] =
                (float)((v - mean) * rstd);
        }
    }
}

// ---------------------------------------------------------------------------
extern "C" void kernel_launch(void* const* d_in, const int* in_sizes, int n_in,
                              void* d_out, int out_size, void* d_ws,
                              size_t ws_size, hipStream_t stream) {
    const float* x  = (const float*)d_in[0];
    const float* wq = (const float*)d_in[1];
    const float* wk = (const float*)d_in[2];
    const float* wv = (const float*)d_in[3];
    const float* wo = (const float*)d_in[4];
    float* out = (float*)d_out;

    float* ws  = (float*)d_ws;
    float* Qf  = ws;                         // pre-BN Q, then GEMM2 out
    float* Kf  = ws + (size_t)TSD_;
    float* Vf  = ws + (size_t)2 * TSD_;
    float* QK  = ws + (size_t)3 * TSD_;      // 3072 floats
    unsigned char* QKm = (unsigned char*)(QK + T_ * D_);  // 3072 B mask (+pad)
    unsigned char* Sx  = QKm + 4096;         // init spikes; reused as Qs
    unsigned char* Ks  = Sx + (size_t)TSD_;
    unsigned char* Vs  = Ks + (size_t)TSD_;
    unsigned char* Bp  = Vs + (size_t)TSD_;  // packed weights, 9.4 MB
    unsigned char* Qs  = Sx;                 // GEMM1 consumed Sx before bn_if

    // 0) zero QK accumulator; pack all 4 weight matrices
    hipMemsetAsync(QK, 0, T_ * D_ * sizeof(float), stream);
    k_prep_w<<<dim3(589824 / 256, 4), 256, 0, stream>>>(wq, wk, wv, wo, Bp);
    // 1) init spikes (int8)
    k_ifnode_x<<<SD_ / (4 * 256), 256, 0, stream>>>(x, Sx);
    // 2) Q/K/V GEMMs on matrix cores (exact fixed-point, LDS dbuf)
    k_gemm_i8<<<dim3(64, 12, 3), 256, 0, stream>>>(Sx, Bp, nullptr,
                                                   Qf, Kf, Vf, 0);
    // 3) BN + IF -> int8 spikes (Qs aliases Sx)
    k_bn_if<<<dim3(S_, 3), 256, 0, stream>>>(Qf, Kf, Vf, Qs, Ks, Vs);
    // 4) talking-heads reduce over S (exact integer atomics)
    k_qk<<<T_ * H_ * 16, 256, 0, stream>>>(Qs, Ks, QK);
    // 5) IF on QK -> int8 mask
    k_if_qk<<<3, 256, 0, stream>>>(QK, QKm);
    // 6) out_pre = (Vs & QKm) @ wo -> Qf   (mask fused into A-path)
    k_gemm_i8<<<dim3(64, 12, 1), 256, 0, stream>>>(Vs, Bp, QKm, Qf, Qf, Qf, 3);
    // 7) final BN -> d_out
    k_bn_out<<<S_, 256, 0, stream>>>(Qf, out);
}